// Round 14
// baseline (121.041 us; speedup 1.0000x reference)
//
#include <hip/hip_runtime.h>

namespace {
constexpr int N_ELEMS = 262144;
constexpr int N_NODES = 263169;
constexpr int BLK     = 256;
constexpr int GRID    = 2048;                 // fills all wave slots
constexpr int NT      = GRID * BLK;           // 524288 threads; 2 units each

// folded material constants (fp32, match reference math)
constexpr float GC_2L0  = 0.09f;
constexpr float L0SQ    = 0.015f * 0.015f;
constexpr float MU_     = 80.76923076923077f;
constexpr float K_MOD   = 175.0f;
constexpr float PENALTY = 1799.82f;
}

typedef float vfloat4 __attribute__((ext_vector_type(4)));

__device__ __forceinline__ float waveReduce(float x) {
#pragma unroll
    for (int off = 32; off; off >>= 1) x += __shfl_down(x, off, 64);
    return x;
}

__global__ __launch_bounds__(256) void fused_energy(
    const float* __restrict__ u, const float* __restrict__ v,
    const float* __restrict__ c, const float* __restrict__ prev_c,
    const int* __restrict__ conn,
    const float* __restrict__ Nf, const float* __restrict__ dNdx,
    const float* __restrict__ B, const float* __restrict__ vol,
    float* __restrict__ partials, unsigned int* __restrict__ counter,
    float* __restrict__ out)
{
    const int k  = threadIdx.x;
    const int t  = blockIdx.x * BLK + k;      // unit A, also node id
    const int t2 = t + NT;                    // unit B

    const vfloat4* Nf4 = reinterpret_cast<const vfloat4*>(Nf);
    const vfloat4* Df4 = reinterpret_cast<const vfloat4*>(dNdx);
    const vfloat4* Bf4 = reinterpret_cast<const vfloat4*>(B);

    // ---- all independent loads issued up front ---------------------------
    const int ia = conn[t];                   // lane-linear index loads
    const int ib = conn[t2];

    const vfloat4 NrA = Nf4[t],        NrB = Nf4[t2];
    const vfloat4 dxA = Df4[2ll * t],  dyA = Df4[2ll * t + 1];
    const vfloat4 dxB = Df4[2ll * t2], dyB = Df4[2ll * t2 + 1];
    const long long b6A = 6ll * t, b6B = 6ll * t2;
    const vfloat4 a0 = Bf4[b6A + 0], a1 = Bf4[b6A + 1], a2 = Bf4[b6A + 2];
    const vfloat4 a3 = Bf4[b6A + 3], a4 = Bf4[b6A + 4], a5 = Bf4[b6A + 5];
    const vfloat4 q0 = Bf4[b6B + 0], q1 = Bf4[b6B + 1], q2 = Bf4[b6B + 2];
    const vfloat4 q3 = Bf4[b6B + 3], q4 = Bf4[b6B + 4], q5 = Bf4[b6B + 5];
    const float volA = vol[t], volB = vol[t2];

    // nodal gathers (c/u/v are L2-resident, ~1 MB each)
    const float cA = c[ia], uA = u[ia], vA = v[ia];
    const float cB = c[ib], uB = u[ib], vB = v[ib];

    // nodal irreversibility term (NT > N_NODES, so t covers all nodes)
    float Eirr = 0.f;
    if (t < N_NODES) {
        const float d = fmaxf(prev_c[t] - c[t], 0.f);
        Eirr = 0.5f * PENALTY * d * d;
    }

    // ---- quad-shuffle redistribution (lane 4a+j holds node j) ------------
    const int base = k & ~3;
    const float cA0 = __shfl(cA, base),     cA1 = __shfl(cA, base + 1);
    const float cA2 = __shfl(cA, base + 2), cA3 = __shfl(cA, base + 3);
    const float uA0 = __shfl(uA, base),     uA1 = __shfl(uA, base + 1);
    const float uA2 = __shfl(uA, base + 2), uA3 = __shfl(uA, base + 3);
    const float vA0 = __shfl(vA, base),     vA1 = __shfl(vA, base + 1);
    const float vA2 = __shfl(vA, base + 2), vA3 = __shfl(vA, base + 3);
    const float cB0 = __shfl(cB, base),     cB1 = __shfl(cB, base + 1);
    const float cB2 = __shfl(cB, base + 2), cB3 = __shfl(cB, base + 3);
    const float uB0 = __shfl(uB, base),     uB1 = __shfl(uB, base + 1);
    const float uB2 = __shfl(uB, base + 2), uB3 = __shfl(uB, base + 3);
    const float vB0 = __shfl(vB, base),     vB1 = __shfl(vB, base + 1);
    const float vB2 = __shfl(vB, base + 2), vB3 = __shfl(vB, base + 3);

    // ---- compute ---------------------------------------------------------
    float Eel = 0.f, Efr = 0.f;
    {   // unit A
        const float o0 = 1.f - cA0, o1 = 1.f - cA1, o2 = 1.f - cA2, o3 = 1.f - cA3;
        const float omc = NrA.x * o0 + NrA.y * o1 + NrA.z * o2 + NrA.w * o3;
        const float g = omc * omc, cip = 1.f - omc;
        const float gx = dxA.x * cA0 + dxA.y * cA1 + dxA.z * cA2 + dxA.w * cA3;
        const float gy = dyA.x * cA0 + dyA.y * cA1 + dyA.z * cA2 + dyA.w * cA3;
        Efr += GC_2L0 * (cip * cip + L0SQ * (gx * gx + gy * gy)) * volA;

        const float exx = a0.x * uA0 + a0.y * vA0 + a0.z * uA1 + a0.w * vA1
                        + a1.x * uA2 + a1.y * vA2 + a1.z * uA3 + a1.w * vA3;
        const float eyy = a2.x * uA0 + a2.y * vA0 + a2.z * uA1 + a2.w * vA1
                        + a3.x * uA2 + a3.y * vA2 + a3.z * uA3 + a3.w * vA3;
        const float gxy = a4.x * uA0 + a4.y * vA0 + a4.z * uA1 + a4.w * vA1
                        + a5.x * uA2 + a5.y * vA2 + a5.z * uA3 + a5.w * vA3;
        const float exy = 0.5f * gxy;
        const float tr = exx + eyy, tr3 = tr * (1.f / 3.f);
        const float dxx = exx - tr3, dyy = eyy - tr3, dzz = -tr3;
        const float dev2 = dxx * dxx + dyy * dyy + dzz * dzz + 2.f * exy * exy;
        const float trp = fmaxf(tr, 0.f), trn = fminf(tr, 0.f);
        Eel += ((0.5f * K_MOD * trp * trp + MU_ * dev2) * g
                + 0.5f * K_MOD * trn * trn) * volA;
    }
    {   // unit B
        const float o0 = 1.f - cB0, o1 = 1.f - cB1, o2 = 1.f - cB2, o3 = 1.f - cB3;
        const float omc = NrB.x * o0 + NrB.y * o1 + NrB.z * o2 + NrB.w * o3;
        const float g = omc * omc, cip = 1.f - omc;
        const float gx = dxB.x * cB0 + dxB.y * cB1 + dxB.z * cB2 + dxB.w * cB3;
        const float gy = dyB.x * cB0 + dyB.y * cB1 + dyB.z * cB2 + dyB.w * cB3;
        Efr += GC_2L0 * (cip * cip + L0SQ * (gx * gx + gy * gy)) * volB;

        const float exx = q0.x * uB0 + q0.y * vB0 + q0.z * uB1 + q0.w * vB1
                        + q1.x * uB2 + q1.y * vB2 + q1.z * uB3 + q1.w * vB3;
        const float eyy = q2.x * uB0 + q2.y * vB0 + q2.z * uB1 + q2.w * vB1
                        + q3.x * uB2 + q3.y * vB2 + q3.z * uB3 + q3.w * vB3;
        const float gxy = q4.x * uB0 + q4.y * vB0 + q4.z * uB1 + q4.w * vB1
                        + q5.x * uB2 + q5.y * vB2 + q5.z * uB3 + q5.w * vB3;
        const float exy = 0.5f * gxy;
        const float tr = exx + eyy, tr3 = tr * (1.f / 3.f);
        const float dxx = exx - tr3, dyy = eyy - tr3, dzz = -tr3;
        const float dev2 = dxx * dxx + dyy * dyy + dzz * dzz + 2.f * exy * exy;
        const float trp = fmaxf(tr, 0.f), trn = fminf(tr, 0.f);
        Eel += ((0.5f * K_MOD * trp * trp + MU_ * dev2) * g
                + 0.5f * K_MOD * trn * trn) * volB;
    }

    // ---- block reduction -> partial store --------------------------------
    Eel  = waveReduce(Eel);
    Efr  = waveReduce(Efr);
    Eirr = waveReduce(Eirr);
    __shared__ float sE[4], sF[4], sI[4];
    const int lane = k & 63, wid = k >> 6;
    if (lane == 0) { sE[wid] = Eel; sF[wid] = Efr; sI[wid] = Eirr; }
    __syncthreads();

    __shared__ int isLast;
    if (k == 0) {
        float* p = partials + 3ll * blockIdx.x;
        p[0] = sE[0] + sE[1] + sE[2] + sE[3];
        p[1] = sF[0] + sF[1] + sF[2] + sF[3];
        p[2] = sI[0] + sI[1] + sI[2] + sI[3];
        __threadfence();                                   // publish partials
        const unsigned int old = atomicAdd(counter, 1u);
        isLast = (old == GRID - 1) ? 1 : 0;
    }
    __syncthreads();

    // ---- last arriving block performs the final reduction ----------------
    if (isLast) {
        __threadfence();                                   // acquire partials
        float s0 = 0.f, s1 = 0.f, s2 = 0.f;
        for (int i = k; i < GRID; i += BLK) {
            const float* p = partials + 3ll * i;
            s0 += p[0]; s1 += p[1]; s2 += p[2];
        }
        s0 = waveReduce(s0);
        s1 = waveReduce(s1);
        s2 = waveReduce(s2);
        __shared__ float rA[4], rB[4], rC[4];
        if (lane == 0) { rA[wid] = s0; rB[wid] = s1; rC[wid] = s2; }
        __syncthreads();
        if (k == 0) {
            out[0] = rA[0] + rA[1] + rA[2] + rA[3];
            out[1] = rB[0] + rB[1] + rB[2] + rB[3];
            out[2] = rC[0] + rC[1] + rC[2] + rC[3];
        }
    }
}

extern "C" void kernel_launch(void* const* d_in, const int* in_sizes, int n_in,
                              void* d_out, int out_size, void* d_ws, size_t ws_size,
                              hipStream_t stream) {
    const float* u      = (const float*)d_in[0];
    const float* v      = (const float*)d_in[1];
    const float* c      = (const float*)d_in[2];
    const float* prev_c = (const float*)d_in[3];
    const int*   conn   = (const int*)d_in[4];
    const float* Nf     = (const float*)d_in[5];
    const float* dNdx   = (const float*)d_in[6];
    const float* B      = (const float*)d_in[7];
    const float* vol    = (const float*)d_in[8];
    float* out = (float*)d_out;

    float* partials = (float*)d_ws;                       // 2048*3 floats
    unsigned int* counter = (unsigned int*)(partials + 3 * GRID);

    hipMemsetAsync(counter, 0, sizeof(unsigned int), stream);
    fused_energy<<<GRID, BLK, 0, stream>>>(
        u, v, c, prev_c, conn, Nf, dNdx, B, vol, partials, counter, out);
}

// Round 15
// 50.964 us; speedup vs baseline: 2.3750x; 2.3750x over previous
//
#include <hip/hip_runtime.h>

namespace {
constexpr int N_ELEMS = 262144;
constexpr int N_NODES = 263169;
constexpr int N_UNITS = N_ELEMS * 4;          // 1048576 (e, ip) units
constexpr int BLK     = 256;
constexpr int GRID1   = 1024;                 // gather_pack blocks
constexpr int GRID2   = 1024;                 // stream_energy blocks
constexpr int STR     = GRID2 * BLK;          // 262144; N_UNITS = 4*STR exactly

// ws layout (floats): packed element records, then partials
constexpr long long WSP_F  = 12LL * N_ELEMS;            // 12.58 MB
constexpr long long P2_OFF = WSP_F;                     // 2*GRID2 floats
constexpr long long PI_OFF = P2_OFF + 2LL * GRID2;      // GRID1 floats

// folded material constants (fp32, match reference math)
constexpr float GC_2L0  = 0.09f;
constexpr float L0SQ    = 0.015f * 0.015f;
constexpr float MU_     = 80.76923076923077f;
constexpr float K_MOD   = 175.0f;
constexpr float PENALTY = 1799.82f;
}

typedef float vfloat4 __attribute__((ext_vector_type(4)));

__device__ __forceinline__ float waveReduce(float x) {
#pragma unroll
    for (int off = 32; off; off >>= 1) x += __shfl_down(x, off, 64);
    return x;
}

// ---------------------------------------------------------------------------
// Phase 1: gather c/u/v per (element, node-slot) into packed 48B/element
// records; also the nodal irreversibility penalty. (unchanged from R13)
// ---------------------------------------------------------------------------
__global__ __launch_bounds__(256) void gather_pack(
    const float* __restrict__ u, const float* __restrict__ v,
    const float* __restrict__ c, const float* __restrict__ prev_c,
    const int* __restrict__ conn,
    float* __restrict__ wsP, float* __restrict__ partialsI)
{
    const int t0 = blockIdx.x * BLK + threadIdx.x;
    const int stride = GRID1 * BLK;

    float Eirr = 0.f;
    for (int n = t0; n < N_NODES; n += stride) {
        const float d = fmaxf(prev_c[n] - c[n], 0.f);
        Eirr += 0.5f * PENALTY * d * d;
    }

    for (int w = t0; w < N_UNITS; w += stride) {
        const int e  = w >> 2;
        const int ip = w & 3;
        const int idx = conn[w];               // lane-linear index load
        wsP[12 * e + ip]     = c[idx];         // gathers hit L2-resident arrays
        wsP[12 * e + 4 + ip] = u[idx];
        wsP[12 * e + 8 + ip] = v[idx];
    }

    Eirr = waveReduce(Eirr);
    __shared__ float sI[4];
    const int lane = threadIdx.x & 63, wid = threadIdx.x >> 6;
    if (lane == 0) sI[wid] = Eirr;
    __syncthreads();
    if (threadIdx.x == 0)
        partialsI[blockIdx.x] = sI[0] + sI[1] + sI[2] + sI[3];
}

// ---------------------------------------------------------------------------
// Phase 2: streaming energy, register-double-buffered. Straight-line code:
// loads for unit t+1 are issued BEFORE compute of unit t (counted vmcnt keeps
// them in flight across the compute). No LDS, no barriers, no shuffles.
// ---------------------------------------------------------------------------
struct Unit {
    vfloat4 cv, uv, vv, Nr, dx, dy, b0, b1, b2, b3, b4, b5;
    float vip;
};

__global__ __launch_bounds__(256, 2) void stream_energy(
    const float* __restrict__ wsP,
    const float* __restrict__ Nf, const float* __restrict__ dNdx,
    const float* __restrict__ B, const float* __restrict__ vol,
    float* __restrict__ partials)
{
    const vfloat4* W   = reinterpret_cast<const vfloat4*>(wsP);
    const vfloat4* Nf4 = reinterpret_cast<const vfloat4*>(Nf);
    const vfloat4* Df4 = reinterpret_cast<const vfloat4*>(dNdx);
    const vfloat4* Bf4 = reinterpret_cast<const vfloat4*>(B);

    const int gt = blockIdx.x * BLK + threadIdx.x;

    float Eel = 0.f, Efr = 0.f;

    auto load = [&](Unit& r, int unit) {
        const int e = unit >> 2;
        r.cv = W[3 * e]; r.uv = W[3 * e + 1]; r.vv = W[3 * e + 2];
        r.Nr = Nf4[unit];
        r.dx = Df4[2ll * unit]; r.dy = Df4[2ll * unit + 1];
        const long long b6 = 6ll * unit;
        r.b0 = Bf4[b6 + 0]; r.b1 = Bf4[b6 + 1]; r.b2 = Bf4[b6 + 2];
        r.b3 = Bf4[b6 + 3]; r.b4 = Bf4[b6 + 4]; r.b5 = Bf4[b6 + 5];
        r.vip = vol[unit];
    };

    auto comp = [&](const Unit& r) {
        const float o0 = 1.f - r.cv.x, o1 = 1.f - r.cv.y;
        const float o2 = 1.f - r.cv.z, o3 = 1.f - r.cv.w;
        const float omc = r.Nr.x * o0 + r.Nr.y * o1 + r.Nr.z * o2 + r.Nr.w * o3;
        const float deg = omc * omc;
        const float cip = 1.f - omc;
        const float gx = r.dx.x * r.cv.x + r.dx.y * r.cv.y
                       + r.dx.z * r.cv.z + r.dx.w * r.cv.w;
        const float gy = r.dy.x * r.cv.x + r.dy.y * r.cv.y
                       + r.dy.z * r.cv.z + r.dy.w * r.cv.w;
        Efr += GC_2L0 * (cip * cip + L0SQ * (gx * gx + gy * gy)) * r.vip;

        const float exx = r.b0.x * r.uv.x + r.b0.y * r.vv.x + r.b0.z * r.uv.y + r.b0.w * r.vv.y
                        + r.b1.x * r.uv.z + r.b1.y * r.vv.z + r.b1.z * r.uv.w + r.b1.w * r.vv.w;
        const float eyy = r.b2.x * r.uv.x + r.b2.y * r.vv.x + r.b2.z * r.uv.y + r.b2.w * r.vv.y
                        + r.b3.x * r.uv.z + r.b3.y * r.vv.z + r.b3.z * r.uv.w + r.b3.w * r.vv.w;
        const float gxy = r.b4.x * r.uv.x + r.b4.y * r.vv.x + r.b4.z * r.uv.y + r.b4.w * r.vv.y
                        + r.b5.x * r.uv.z + r.b5.y * r.vv.z + r.b5.z * r.uv.w + r.b5.w * r.vv.w;
        const float exy = 0.5f * gxy;
        const float tr  = exx + eyy, tr3 = tr * (1.f / 3.f);
        const float dxx = exx - tr3, dyy = eyy - tr3, dzz = -tr3;
        const float dev2 = dxx * dxx + dyy * dyy + dzz * dzz + 2.f * exy * exy;
        const float trp = fmaxf(tr, 0.f), trn = fminf(tr, 0.f);
        Eel += ((0.5f * K_MOD * trp * trp + MU_ * dev2) * deg
                + 0.5f * K_MOD * trn * trn) * r.vip;
    };

    // depth-2 software pipeline over the 4 units this thread owns
    Unit A, Bu;
    load(A,  gt);
    load(Bu, gt + STR);
    comp(A);
    load(A,  gt + 2 * STR);
    comp(Bu);
    load(Bu, gt + 3 * STR);
    comp(A);
    comp(Bu);

    Eel = waveReduce(Eel);
    Efr = waveReduce(Efr);
    __shared__ float sE[4], sF[4];
    const int lane = threadIdx.x & 63, wid = threadIdx.x >> 6;
    if (lane == 0) { sE[wid] = Eel; sF[wid] = Efr; }
    __syncthreads();
    if (threadIdx.x == 0) {
        float* p = partials + 2ll * blockIdx.x;
        p[0] = sE[0] + sE[1] + sE[2] + sE[3];
        p[1] = sF[0] + sF[1] + sF[2] + sF[3];
    }
}

__global__ __launch_bounds__(256) void final_reduce(
    const float* __restrict__ partials, const float* __restrict__ partialsI,
    float* __restrict__ out)
{
    float s0 = 0.f, s1 = 0.f, s2 = 0.f;
    for (int i = threadIdx.x; i < GRID2; i += 256) {
        s0 += partials[2ll * i];
        s1 += partials[2ll * i + 1];
    }
    for (int i = threadIdx.x; i < GRID1; i += 256)
        s2 += partialsI[i];
    s0 = waveReduce(s0);
    s1 = waveReduce(s1);
    s2 = waveReduce(s2);
    __shared__ float sA[4], sB[4], sC[4];
    const int lane = threadIdx.x & 63, wid = threadIdx.x >> 6;
    if (lane == 0) { sA[wid] = s0; sB[wid] = s1; sC[wid] = s2; }
    __syncthreads();
    if (threadIdx.x == 0) {
        out[0] = sA[0] + sA[1] + sA[2] + sA[3];
        out[1] = sB[0] + sB[1] + sB[2] + sB[3];
        out[2] = sC[0] + sC[1] + sC[2] + sC[3];
    }
}

extern "C" void kernel_launch(void* const* d_in, const int* in_sizes, int n_in,
                              void* d_out, int out_size, void* d_ws, size_t ws_size,
                              hipStream_t stream) {
    const float* u      = (const float*)d_in[0];
    const float* v      = (const float*)d_in[1];
    const float* c      = (const float*)d_in[2];
    const float* prev_c = (const float*)d_in[3];
    const int*   conn   = (const int*)d_in[4];
    const float* Nf     = (const float*)d_in[5];
    const float* dNdx   = (const float*)d_in[6];
    const float* B      = (const float*)d_in[7];
    const float* vol    = (const float*)d_in[8];
    float* out = (float*)d_out;

    float* wsP       = (float*)d_ws;          // 12.58 MB packed records
    float* partials  = wsP + P2_OFF;          // 2*1024 floats
    float* partialsI = wsP + PI_OFF;          // 1024 floats

    gather_pack<<<GRID1, BLK, 0, stream>>>(u, v, c, prev_c, conn, wsP, partialsI);
    stream_energy<<<GRID2, BLK, 0, stream>>>(wsP, Nf, dNdx, B, vol, partials);
    final_reduce<<<1, BLK, 0, stream>>>(partials, partialsI, out);
}

// Round 16
// 50.790 us; speedup vs baseline: 2.3831x; 1.0034x over previous
//
#include <hip/hip_runtime.h>

namespace {
constexpr int N_ELEMS = 262144;
constexpr int N_NODES = 263169;
constexpr int BLK     = 256;
constexpr int EPB     = 64;                  // elements per block
constexpr int GRID    = N_ELEMS / EPB;       // 4096

// folded material constants (fp32, match reference math)
constexpr float GC_2L0  = 0.09f;
constexpr float L0SQ    = 0.015f * 0.015f;
constexpr float MU_     = 80.76923076923077f;
constexpr float K_MOD   = 175.0f;
constexpr float PENALTY = 1799.82f;
}

typedef float vfloat4 __attribute__((ext_vector_type(4)));

// Async global->LDS copy, 16B per lane: data lands at lds_base + lane*16.
// No VGPR destination -> in-flight bytes are NOT bounded by the register file.
__device__ __forceinline__ void async_copy16(void* lds_base, const void* gsrc) {
    __builtin_amdgcn_global_load_lds(
        (const __attribute__((address_space(1))) void*)(void*)gsrc,
        (__attribute__((address_space(3))) void*)lds_base,
        16, 0, 0);
}

__device__ __forceinline__ float waveReduce(float x) {
#pragma unroll
    for (int off = 32; off; off >>= 1) x += __shfl_down(x, off, 64);
    return x;
}

__global__ __launch_bounds__(256) void fused_energy(
    const float* __restrict__ u, const float* __restrict__ v,
    const float* __restrict__ c, const float* __restrict__ prev_c,
    const int* __restrict__ conn,
    const float* __restrict__ Nf, const float* __restrict__ dNdx,
    const float* __restrict__ B, const float* __restrict__ vol,
    float* __restrict__ partials)
{
    // Linear (global-order) tiles, filled by global_load_lds.
    __shared__ vfloat4 aB[1536];      // 24 KB  B tile   [elem][ip][6 f4]
    __shared__ vfloat4 aD[512];       //  8 KB  dNdx     [elem][ip][2 f4]
    __shared__ vfloat4 aN[256];       //  4 KB  N        [elem][ip] f4
    __shared__ vfloat4 aV[64];        //  1 KB  vol      [unit] f32
    __shared__ float  ldsN[12 * 66];  //  3 KB  gathered c/u/v (padded)

    const int k    = threadIdx.x;
    const int wid  = k >> 6, lane = k & 63;
    const int ebase = blockIdx.x * EPB;
    const int t     = blockIdx.x * BLK + k;       // nodal term id

    const vfloat4* Bg = reinterpret_cast<const vfloat4*>(B)    + (long long)ebase * 24;
    const vfloat4* Dg = reinterpret_cast<const vfloat4*>(dNdx) + (long long)ebase * 8;
    const vfloat4* Ng = reinterpret_cast<const vfloat4*>(Nf)   + (long long)ebase * 4;
    const vfloat4* Vg = reinterpret_cast<const vfloat4*>(vol)  + (long long)ebase;  // 64 f4

    // ---- async staging: 37 x 1KB wave-instructions, zero VGPR dests ------
#pragma unroll
    for (int i = 0; i < 6; ++i) {                 // B: 24 slots of 64 f4
        const int s = i * 4 + wid;
        async_copy16(&aB[s * 64], Bg + s * 64 + lane);
    }
#pragma unroll
    for (int i = 0; i < 2; ++i) {                 // dNdx: 8 slots
        const int s = i * 4 + wid;
        async_copy16(&aD[s * 64], Dg + s * 64 + lane);
    }
    async_copy16(&aN[wid * 64], Ng + wid * 64 + lane);   // N: 4 slots
    if (wid == 0) async_copy16(&aV[0], Vg + lane);       // vol: 1 slot

    // ---- register-path gathers (c/u/v ~1MB each, L2-resident) ------------
    const int m = k >> 2, ip = k & 3;
    const int idx = conn[4ll * ebase + k];        // lane-linear index load
    ldsN[ip * 66 + m]       = c[idx];
    ldsN[(4 + ip) * 66 + m] = u[idx];
    ldsN[(8 + ip) * 66 + m] = v[idx];

    float Eirr = 0.f;
    if (t < N_NODES) {
        const float d = fmaxf(prev_c[t] - c[t], 0.f);
        Eirr = 0.5f * PENALTY * d * d;
    }

    __syncthreads();   // compiler emits s_waitcnt vmcnt(0) lgkmcnt(0) first

    // ---- read this unit's data from LDS ----------------------------------
    const float c0 = ldsN[0 * 66 + m], c1 = ldsN[1 * 66 + m];
    const float c2 = ldsN[2 * 66 + m], c3 = ldsN[3 * 66 + m];
    const float u0 = ldsN[4 * 66 + m], u1 = ldsN[5 * 66 + m];
    const float u2 = ldsN[6 * 66 + m], u3 = ldsN[7 * 66 + m];
    const float v0 = ldsN[8 * 66 + m], v1 = ldsN[9 * 66 + m];
    const float v2 = ldsN[10 * 66 + m], v3 = ldsN[11 * 66 + m];

    const vfloat4 Nr = aN[m * 4 + ip];
    const vfloat4 dx = aD[m * 8 + ip * 2];
    const vfloat4 dy = aD[m * 8 + ip * 2 + 1];
    const int b0i = m * 24 + ip * 6;
    const vfloat4 b0 = aB[b0i + 0], b1 = aB[b0i + 1], b2 = aB[b0i + 2];
    const vfloat4 b3 = aB[b0i + 3], b4 = aB[b0i + 4], b5 = aB[b0i + 5];
    const float vip = reinterpret_cast<const float*>(aV)[k];

    // ---- compute one (e, ip) unit ----------------------------------------
    const float o0 = 1.f - c0, o1 = 1.f - c1, o2 = 1.f - c2, o3 = 1.f - c3;
    const float omc = Nr.x * o0 + Nr.y * o1 + Nr.z * o2 + Nr.w * o3;
    const float g   = omc * omc;
    const float cip = 1.f - omc;
    const float gx  = dx.x * c0 + dx.y * c1 + dx.z * c2 + dx.w * c3;
    const float gy  = dy.x * c0 + dy.y * c1 + dy.z * c2 + dy.w * c3;
    float Efr = GC_2L0 * (cip * cip + L0SQ * (gx * gx + gy * gy)) * vip;

    const float exx = b0.x * u0 + b0.y * v0 + b0.z * u1 + b0.w * v1
                    + b1.x * u2 + b1.y * v2 + b1.z * u3 + b1.w * v3;
    const float eyy = b2.x * u0 + b2.y * v0 + b2.z * u1 + b2.w * v1
                    + b3.x * u2 + b3.y * v2 + b3.z * u3 + b3.w * v3;
    const float gxy = b4.x * u0 + b4.y * v0 + b4.z * u1 + b4.w * v1
                    + b5.x * u2 + b5.y * v2 + b5.z * u3 + b5.w * v3;
    const float exy = 0.5f * gxy;
    const float tr  = exx + eyy, tr3 = tr * (1.f / 3.f);
    const float dxx = exx - tr3, dyy = eyy - tr3, dzz = -tr3;
    const float dev2 = dxx * dxx + dyy * dyy + dzz * dzz + 2.f * exy * exy;
    const float trp = fmaxf(tr, 0.f), trn = fminf(tr, 0.f);
    float Eel = ((0.5f * K_MOD * trp * trp + MU_ * dev2) * g
                 + 0.5f * K_MOD * trn * trn) * vip;

    // ---- block reduction -> contention-free partial store ----------------
    Eel  = waveReduce(Eel);
    Efr  = waveReduce(Efr);
    Eirr = waveReduce(Eirr);
    __shared__ float sE[4], sF[4], sI[4];
    if (lane == 0) { sE[wid] = Eel; sF[wid] = Efr; sI[wid] = Eirr; }
    __syncthreads();
    if (k == 0) {
        float* p = partials + 3ll * blockIdx.x;
        p[0] = sE[0] + sE[1] + sE[2] + sE[3];
        p[1] = sF[0] + sF[1] + sF[2] + sF[3];
        p[2] = sI[0] + sI[1] + sI[2] + sI[3];
    }
}

__global__ __launch_bounds__(256) void final_reduce(
    const float* __restrict__ partials, float* __restrict__ out)
{
    float s0 = 0.f, s1 = 0.f, s2 = 0.f;
    for (int i = threadIdx.x; i < GRID; i += 256) {
        const float* p = partials + 3ll * i;
        s0 += p[0]; s1 += p[1]; s2 += p[2];
    }
    s0 = waveReduce(s0);
    s1 = waveReduce(s1);
    s2 = waveReduce(s2);
    __shared__ float sA[4], sB[4], sC[4];
    const int lane = threadIdx.x & 63, wid = threadIdx.x >> 6;
    if (lane == 0) { sA[wid] = s0; sB[wid] = s1; sC[wid] = s2; }
    __syncthreads();
    if (threadIdx.x == 0) {
        out[0] = sA[0] + sA[1] + sA[2] + sA[3];
        out[1] = sB[0] + sB[1] + sB[2] + sB[3];
        out[2] = sC[0] + sC[1] + sC[2] + sC[3];
    }
}

extern "C" void kernel_launch(void* const* d_in, const int* in_sizes, int n_in,
                              void* d_out, int out_size, void* d_ws, size_t ws_size,
                              hipStream_t stream) {
    const float* u      = (const float*)d_in[0];
    const float* v      = (const float*)d_in[1];
    const float* c      = (const float*)d_in[2];
    const float* prev_c = (const float*)d_in[3];
    const int*   conn   = (const int*)d_in[4];
    const float* Nf     = (const float*)d_in[5];
    const float* dNdx   = (const float*)d_in[6];
    const float* B      = (const float*)d_in[7];
    const float* vol    = (const float*)d_in[8];
    float* out      = (float*)d_out;
    float* partials = (float*)d_ws;              // 4096*3 floats = 48 KB

    fused_energy<<<GRID, BLK, 0, stream>>>(
        u, v, c, prev_c, conn, Nf, dNdx, B, vol, partials);
    final_reduce<<<1, BLK, 0, stream>>>(partials, out);
}